// Round 10
// baseline (319.110 us; speedup 1.0000x reference)
//
#include <hip/hip_runtime.h>
#include <math.h>

// FastGRNN fused recurrence — v7: v6 + producer-side hi/lo split in LDS.
// v6 post-mortem: 4660 cyc/CU/step wall; VALU 2100 (45%) dominated by the
// READ-side hi/lo A-frag split (~100 instr/wave/step); 6.5M bank-conflict
// cycles from the [row][132] f32 layout; MFMA only 19%.
// v7 changes:
//  (a) H stored in LDS as TWO bf16 planes (hi, lo) packed per k-pair u32 —
//      same bytes as f32, but ds_read_b128 IS the MFMA A-frag (zero VALU).
//      Producer splits its own 8 values (4 ops each + 16 ds_write_b16).
//  (b) XOR swizzle stored_pair = p ^ ((row&3)<<2): bijective per row ->
//      never-written logical pairs 56..63 stay zero; kills 4-way conflicts.
//  (c) split accumulators (even/odd kt) halve the MFMA dep chain.
//  (d) gates: h = 2*rcp(1+p)-1, no clamp (inf path gives exact limits).
// Everything else (B-frags pinned in regs, 3-product hi/lo MFMA, 1 barrier/
// step, block = 4 waves x 16 rows, grid 512) as v6 (validated 3.9e-3).

typedef __attribute__((ext_vector_type(8))) short short8_t;
typedef __attribute__((ext_vector_type(4))) float f32x4;

#define TSTEPS 99
#define DIN    32
#define DH     100
#define XROW   3168
#define NCLS   6
#define LOG2E  1.44269504088896340736f

// B-frag pack in ws: F = (jt*5 + kt)*2 + s; kt 0..3 = Ueff k-tiles, kt 4 = WW.
#define NFRAG  70
#define OFF_EG (NFRAG * 256)
#define OFF_EU (OFF_EG + 128)
#define OFF_SZ (OFF_EU + 128)
#define OFF_SN (OFF_SZ + 1)

__device__ __forceinline__ unsigned cvtpk(float a, float b) {
    unsigned r;
    asm("v_cvt_pk_bf16_f32 %0, %1, %2" : "=v"(r) : "v"(a), "v"(b));
    return r;
}
__device__ __forceinline__ float fbits(unsigned u) { return __int_as_float((int)u); }

union F8 { unsigned u4[4]; short8_t s8; };

__global__ __launch_bounds__(256) void precomp(
    const float* __restrict__ W1, const float* __restrict__ W2,
    const float* __restrict__ U1, const float* __restrict__ U2,
    const float* __restrict__ bg, const float* __restrict__ bu,
    const float* __restrict__ zeta, const float* __restrict__ nu,
    float* __restrict__ ws)
{
    const int i = blockIdx.x * 256 + threadIdx.x;
    if (i < 2240) {                             // one job per (jt,kt,lane)
        const int lane = i & 63, f = i >> 6;    // f = jt*5 + kt, 0..34
        const int jt = f / 5, kt = f % 5;
        const int u = lane & 15, g4 = lane >> 4;
        const int col = jt * 16 + u;
        float v[8];
        #pragma unroll
        for (int e = 0; e < 8; ++e) {
            float s = 0.f;
            if (col < DH) {
                if (kt < 4) {
                    const int k = kt * 32 + g4 * 8 + e;
                    if (k < DH) {
                        #pragma unroll
                        for (int r = 0; r < 25; ++r)
                            s = fmaf(U1[k * 25 + r], U2[r * DH + col], s);
                    }
                } else {
                    const int k = g4 * 8 + e;   // < 32
                    #pragma unroll
                    for (int r = 0; r < 16; ++r)
                        s = fmaf(W1[k * 16 + r], W2[r * DH + col], s);
                }
            }
            v[e] = s * LOG2E;
        }
        unsigned hi[4], lo[4];
        #pragma unroll
        for (int rr = 0; rr < 4; ++rr) {
            const float a = v[2 * rr], b = v[2 * rr + 1];
            const unsigned ph = cvtpk(a, b);
            hi[rr] = ph;
            lo[rr] = cvtpk(a - fbits(ph << 16), b - fbits(ph & 0xffff0000u));
        }
        uint4* B = (uint4*)ws;
        B[(f * 2 + 0) * 64 + lane] = make_uint4(hi[0], hi[1], hi[2], hi[3]);
        B[(f * 2 + 1) * 64 + lane] = make_uint4(lo[0], lo[1], lo[2], lo[3]);
    } else if (i < 2240 + 128) {
        const int p = i - 2240;
        ws[OFF_EG + p] = (p < DH) ? expf(-bg[p]) : 1.f;
    } else if (i < 2240 + 256) {
        const int p = i - 2240 - 128;
        ws[OFF_EU + p] = (p < DH) ? expf(-2.f * bu[p]) : 1.f;
    } else if (i == 2240 + 256) {
        ws[OFF_SZ] = 1.f / (1.f + expf(-zeta[0]));
    } else if (i == 2240 + 257) {
        ws[OFF_SN] = 1.f / (1.f + expf(-nu[0]));
    }
}

__global__ __launch_bounds__(256, 2) void fastgrnn_main(
    const float* __restrict__ x, const float* __restrict__ ws,
    const float* __restrict__ FC, const float* __restrict__ FCbias,
    float* __restrict__ out)
{
    // [buf][plane hi/lo][row][pair 0..67]; pair word = 2 bf16 (k=2p, 2p+1),
    // stored at p ^ ((row&3)<<2). 17.4 KB.
    __shared__ unsigned Hs[2][2][16][68];

    const int tid  = threadIdx.x;
    const int lane = tid & 63;
    const int ww   = __builtin_amdgcn_readfirstlane(tid >> 6);  // 0..3
    const int jn   = (ww == 3) ? 1 : 2;        // j-tiles owned: (2,2,2,1)
    const int u    = lane & 15;
    const int g4   = lane >> 4;
    const int rowbase = blockIdx.x * 16;

    // zero both buffers/planes: initial H=0, and never-written pairs stay 0
    for (int z = tid; z < 2 * 2 * 16 * 68; z += 256) ((unsigned*)Hs)[z] = 0u;

    // ---- one-time: B fragments into pinned regs ----
    F8 Breg[2][5][2];
    #pragma unroll
    for (int jj = 0; jj < 2; ++jj) {
        const int jt = (2 * ww + jj > 6) ? 6 : 2 * ww + jj;  // wave3 dups jt6
        #pragma unroll
        for (int kt = 0; kt < 5; ++kt) {
            #pragma unroll
            for (int s = 0; s < 2; ++s) {
                const int F = (jt * 5 + kt) * 2 + s;
                Breg[jj][kt][s].s8 =
                    *(const short8_t*)((const uint4*)ws + F * 64 + lane);
                asm volatile("" : "+v"(Breg[jj][kt][s].u4[0]),
                                  "+v"(Breg[jj][kt][s].u4[1]),
                                  "+v"(Breg[jj][kt][s].u4[2]),
                                  "+v"(Breg[jj][kt][s].u4[3]));
            }
        }
    }
    float eg_r[2], eu_r[2];
    #pragma unroll
    for (int jj = 0; jj < 2; ++jj) {
        const int jt = (2 * ww + jj > 6) ? 6 : 2 * ww + jj;
        const int unit = jt * 16 + u;
        eg_r[jj] = ws[OFF_EG + unit];
        eu_r[jj] = ws[OFF_EU + unit];
        asm volatile("" : "+v"(eg_r[jj]), "+v"(eu_r[jj]));
    }
    const float sz = ws[OFF_SZ];
    const float sn = ws[OFF_SN];

    const float* __restrict__ xrow = x + (size_t)(rowbase + u) * XROW + g4 * 8;

    const f32x4 zero4 = {0.f, 0.f, 0.f, 0.f};
    f32x4 Hold[2];
    Hold[0] = zero4; Hold[1] = zero4;

    const int ridx0 = (g4 ^ (u & 3)) << 2;     // swizzled read base within row
    unsigned short* const hwbase = (unsigned short*)&Hs[0][0][0][0];
    // halfword strides: buf = 2*16*136, plane = 16*136, row = 136

    __syncthreads();

    for (int t = 0; t < TSTEPS; ++t) {
        const int rb = t & 1, wb = rb ^ 1;

        // x A-frags (2x b128 global, split in VALU — 8 values)
        F8 xhi, xlo;
        {
            const f32x4 xa = *(const f32x4*)(xrow + t * DIN);
            const f32x4 xb = *(const f32x4*)(xrow + t * DIN + 4);
            const float xs[8] = { xa.x, xa.y, xa.z, xa.w, xb.x, xb.y, xb.z, xb.w };
            #pragma unroll
            for (int r = 0; r < 4; ++r) {
                const unsigned ph = cvtpk(xs[2*r], xs[2*r+1]);
                xhi.u4[r] = ph;
                xlo.u4[r] = cvtpk(xs[2*r]   - fbits(ph << 16),
                                  xs[2*r+1] - fbits(ph & 0xffff0000u));
            }
        }

        f32x4 a0[2], a1[2];
        a0[0] = zero4; a0[1] = zero4; a1[0] = zero4; a1[1] = zero4;

        // H A-frags: the b128 read IS the frag (pre-split). even kt -> a0,
        // odd kt -> a1 (halves the MFMA dep chain).
        #pragma unroll
        for (int kt = 0; kt < 4; ++kt) {
            const short8_t Ah = *(const short8_t*)&Hs[rb][0][u][kt * 16 + ridx0];
            const short8_t Al = *(const short8_t*)&Hs[rb][1][u][kt * 16 + ridx0];
            f32x4* acc = (kt & 1) ? a1 : a0;
            #pragma unroll
            for (int jj = 0; jj < 2; ++jj)
                if (jj < jn)
                    acc[jj] = __builtin_amdgcn_mfma_f32_16x16x32_bf16(
                        Al, Breg[jj][kt][0].s8, acc[jj], 0, 0, 0);
            #pragma unroll
            for (int jj = 0; jj < 2; ++jj)
                if (jj < jn)
                    acc[jj] = __builtin_amdgcn_mfma_f32_16x16x32_bf16(
                        Ah, Breg[jj][kt][1].s8, acc[jj], 0, 0, 0);
            #pragma unroll
            for (int jj = 0; jj < 2; ++jj)
                if (jj < jn)
                    acc[jj] = __builtin_amdgcn_mfma_f32_16x16x32_bf16(
                        Ah, Breg[jj][kt][0].s8, acc[jj], 0, 0, 0);
        }
        // x products -> a1
        #pragma unroll
        for (int jj = 0; jj < 2; ++jj)
            if (jj < jn)
                a1[jj] = __builtin_amdgcn_mfma_f32_16x16x32_bf16(
                    xlo.s8, Breg[jj][4][0].s8, a1[jj], 0, 0, 0);
        #pragma unroll
        for (int jj = 0; jj < 2; ++jj)
            if (jj < jn)
                a1[jj] = __builtin_amdgcn_mfma_f32_16x16x32_bf16(
                    xhi.s8, Breg[jj][4][1].s8, a1[jj], 0, 0, 0);
        #pragma unroll
        for (int jj = 0; jj < 2; ++jj)
            if (jj < jn)
                a1[jj] = __builtin_amdgcn_mfma_f32_16x16x32_bf16(
                    xhi.s8, Breg[jj][4][0].s8, a1[jj], 0, 0, 0);

        // gates + H update + pre-split write (own units only)
        unsigned short* const hp = hwbase + wb * (2 * 16 * 136);
        unsigned short* const lp = hp + 16 * 136;
        #pragma unroll
        for (int jj = 0; jj < 2; ++jj) {
            if (jj < jn) {
                const int jt = (2 * ww + jj > 6) ? 6 : 2 * ww + jj;
                const int pbase = jt * 8 + (u >> 1);
                const int hoff  = (u & 1);
                f32x4 hn;
                #pragma unroll
                for (int i = 0; i < 4; ++i) {
                    const float cc = a0[jj][i] + a1[jj][i];    // = c * log2e
                    const float E  = __builtin_amdgcn_exp2f(-cc);
                    const float g  = __builtin_amdgcn_rcpf(fmaf(E, eg_r[jj], 1.f));
                    const float pp = fmaf(E * E, eu_r[jj], 1.f);   // 1 + p
                    const float h  = fmaf(2.f, __builtin_amdgcn_rcpf(pp), -1.f);
                    hn[i] = fmaf(g, Hold[jj][i], fmaf(sn, h, fmaf(-sz, g, sz)));
                }
                Hold[jj] = hn;
                #pragma unroll
                for (int i = 0; i < 4; ++i) {
                    const int r  = g4 * 4 + i;
                    const int ps = pbase ^ (i << 2);           // row&3 == i
                    const float h = hn[i];
                    const unsigned h16 = cvtpk(h, h);
                    const float    hrec = fbits(h16 << 16);
                    const unsigned l16 = cvtpk(h - hrec, h - hrec);
                    hp[r * 136 + ps * 2 + hoff] = (unsigned short)h16;
                    lp[r * 136 + ps * 2 + hoff] = (unsigned short)l16;
                }
            }
        }
        __syncthreads();
    }

    // ---- epilogue: score = H@FC + bias (reconstruct H = hi + lo) ----
    const int fb = TSTEPS & 1;   // final H buffer
    if (tid < 16 * NCLS) {
        const int rl = tid / NCLS, c = tid % NCLS;
        float s = FCbias[c];
        for (int k = 0; k < DH; ++k) {
            const int p  = k >> 1;
            const int ps = p ^ ((rl & 3) << 2);
            const unsigned wh = Hs[fb][0][rl][ps];
            const unsigned wl = Hs[fb][1][rl][ps];
            const float hi = (k & 1) ? fbits(wh & 0xffff0000u) : fbits(wh << 16);
            const float lo = (k & 1) ? fbits(wl & 0xffff0000u) : fbits(wl << 16);
            s = fmaf(hi + lo, FC[k * NCLS + c], s);
        }
        out[(size_t)(rowbase + rl) * NCLS + c] = s;
    }
}

extern "C" void kernel_launch(void* const* d_in, const int* in_sizes, int n_in,
                              void* d_out, int out_size, void* d_ws, size_t ws_size,
                              hipStream_t stream)
{
    const float* x    = (const float*)d_in[0];
    const float* W1   = (const float*)d_in[1];
    const float* W2   = (const float*)d_in[2];
    const float* U1   = (const float*)d_in[3];
    const float* U2   = (const float*)d_in[4];
    const float* bg   = (const float*)d_in[5];
    const float* bu   = (const float*)d_in[6];
    const float* zeta = (const float*)d_in[7];
    const float* nu   = (const float*)d_in[8];
    const float* FC   = (const float*)d_in[9];
    const float* FCb  = (const float*)d_in[10];
    float* ws  = (float*)d_ws;
    float* out = (float*)d_out;

    precomp<<<(2240 + 258 + 255) / 256, 256, 0, stream>>>(
        W1, W2, U1, U2, bg, bu, zeta, nu, ws);
    fastgrnn_main<<<512, 256, 0, stream>>>(x, ws, FC, FCb, out);
}